// Round 2
// baseline (10716.703 us; speedup 1.0000x reference)
//
#include <hip/hip_runtime.h>
#include <cstddef>

// NLM: h=7/255, template 7x7 (TH=3), search 21x21 (SH=10), reflect padding.
// Tile 32x32/block, 256 threads. Per offset:
//   A : d = (u - shifted)^2 into ds (6 elems/thread, u preloaded in regs)
//   Bv: vertical 7-sums with register sliding (threads 0..163, 8 rows each)
//   C : horizontal 7-sums sliding + exp weight + accumulate (1 row x 4 cols)
// All LDS addresses are fixed-register + immediate; inner 21-offset loop
// unrolled so dx folds into ds_read offsets.

constexpr int TS    = 32;
constexpr int XSTR  = 61;       // odd -> <=2-way LDS bank aliasing everywhere
constexpr int XROWS = 59;       // rows 0..57 data, row 58 spare (clamped copy)
constexpr int DSTR  = 41;
constexpr int DS_SZ = 1600;     // rows 0..38, max idx 38*41+40 = 1598
constexpr int VSTR  = 41;
constexpr int VS_SZ = 1312;     // 32 rows, max idx 31*41+40 = 1311

__device__ __forceinline__ int refl(int i, int n) {
    i = (i < 0) ? -i : i;
    return (i >= n) ? (2 * n - 2 - i) : i;
}

__global__ __launch_bounds__(256, 6)
void nlm_kernel(const float* __restrict__ img_all, float* __restrict__ out,
                int H, int W) {
    __shared__ float xs[XROWS * XSTR];
    __shared__ float ds[DS_SZ];
    __shared__ float vs[VS_SZ];

    const int tid = threadIdx.x;
    const int gx0 = blockIdx.x * TS;
    const int gy0 = blockIdx.y * TS;
    const float* img = img_all + (size_t)blockIdx.z * H * W;

    // ---- load xs (clipped to [0,1], reflect indexing); pads clamped so the
    // whole array is initialized (no NaN surprises on garbage paths) ----
    for (int e = tid; e < XROWS * XSTR; e += 256) {
        int i = e / XSTR, j = e - i * XSTR;
        int ii = (i > 57) ? 57 : i;
        int jj = (j > 57) ? 57 : j;
        int gy = refl(gy0 - 13 + ii, H);
        int gx = refl(gx0 - 13 + jj, W);
        float v = img[(size_t)gy * W + gx];
        xs[e] = fminf(fmaxf(v, 0.0f), 1.0f);
    }
    __syncthreads();

    // ---- stage-A constants: 3 pairs = 6 elements over 39x40 region ----
    // element (arow, acol) <-> d at image (gy0+arow-3, gx0+acol-3), box-filter
    // reflection folded into my/mx. u values preloaded (offset-invariant).
    int   ra[6];   // xs dword index at (my-10)*61 + (mx-10); +=61 per oy
    int   wa[3];   // ds write index (even col, pair-adjacent)
    float uv[6];
#pragma unroll
    for (int k = 0; k < 3; ++k) {
        int p     = tid + 256 * k;
        int arow  = p / 20;
        int acol2 = (p - arow * 20) * 2;
        int my  = refl(gy0 + arow - 3, H) - gy0 + 13;
        int mx0 = refl(gx0 + acol2 - 3, W) - gx0 + 13;
        int mx1 = refl(gx0 + acol2 - 2, W) - gx0 + 13;
        uv[2 * k]     = xs[my * XSTR + mx0];
        uv[2 * k + 1] = xs[my * XSTR + mx1];
        ra[2 * k]     = (my - 10) * XSTR + (mx0 - 10);
        ra[2 * k + 1] = (my - 10) * XSTR + (mx1 - 10);
        wa[k] = arow * DSTR + acol2;
    }

    // ---- stage-Bv constants: threads 0..163 = 41 cols x 4 row-groups ----
    const bool bv_act = (tid < 164);
    int rb, wb;
    {
        int t  = bv_act ? tid : 0;
        int g  = t / 41;
        int cc = t - g * 41;
        rb = (g * 8) * DSTR + cc;   // ds reads: rb + i*DSTR, i=0..13
        wb = (g * 8) * VSTR + cc;   // vs writes: wb + i*VSTR, i=0..7
    }

    // ---- stage-C constants: 1 row x 4 cols per thread ----
    const int py = tid >> 3;
    const int c4 = (tid & 7) * 4;
    const int vb = py * VSTR + c4;
    int svb = (py + 3) * XSTR + (c4 + 3);   // shifted-value base at dy=dx=-10

    float ws0 = 0.f, ws1 = 0.f, ws2 = 0.f, ws3 = 0.f;
    float vs0 = 0.f, vs1 = 0.f, vs2 = 0.f, vs3 = 0.f;
    // w = exp(-mean49(d)/H2) = exp2(K * sum49(d))
    const float K = -(65025.0f / 2401.0f) * 1.4426950408889634f;

    for (int oy = 0; oy < 21; ++oy) {
#pragma unroll
        for (int ox = 0; ox < 21; ++ox) {
            // ---- A ----
#pragma unroll
            for (int k = 0; k < 3; ++k) {
                float s0 = xs[ra[2 * k] + ox];
                float s1 = xs[ra[2 * k + 1] + ox];
                float d0 = uv[2 * k] - s0;
                float d1 = uv[2 * k + 1] - s1;
                ds[wa[k]]     = d0 * d0;
                ds[wa[k] + 1] = d1 * d1;
            }
            __syncthreads();

            // ---- Bv: vertical 7-sums, sliding over 8 output rows ----
            if (bv_act) {
                float r0  = ds[rb];
                float r1  = ds[rb + 1 * DSTR];
                float r2  = ds[rb + 2 * DSTR];
                float r3  = ds[rb + 3 * DSTR];
                float r4  = ds[rb + 4 * DSTR];
                float r5  = ds[rb + 5 * DSTR];
                float r6  = ds[rb + 6 * DSTR];
                float r7  = ds[rb + 7 * DSTR];
                float r8  = ds[rb + 8 * DSTR];
                float r9  = ds[rb + 9 * DSTR];
                float r10 = ds[rb + 10 * DSTR];
                float r11 = ds[rb + 11 * DSTR];
                float r12 = ds[rb + 12 * DSTR];
                float r13 = ds[rb + 13 * DSTR];
                float s = ((r0 + r1) + (r2 + r3)) + ((r4 + r5) + r6);
                vs[wb]            = s;
                s += r7  - r0;  vs[wb + 1 * VSTR] = s;
                s += r8  - r1;  vs[wb + 2 * VSTR] = s;
                s += r9  - r2;  vs[wb + 3 * VSTR] = s;
                s += r10 - r3;  vs[wb + 4 * VSTR] = s;
                s += r11 - r4;  vs[wb + 5 * VSTR] = s;
                s += r12 - r5;  vs[wb + 6 * VSTR] = s;
                s += r13 - r6;  vs[wb + 7 * VSTR] = s;
            }
            __syncthreads();

            // ---- C: horizontal sliding + weight + accumulate ----
            float t0 = vs[vb];
            float t1 = vs[vb + 1];
            float t2 = vs[vb + 2];
            float t3 = vs[vb + 3];
            float t4 = vs[vb + 4];
            float t5 = vs[vb + 5];
            float t6 = vs[vb + 6];
            float t7 = vs[vb + 7];
            float t8 = vs[vb + 8];
            float t9 = vs[vb + 9];
            float h0 = ((t0 + t1) + (t2 + t3)) + ((t4 + t5) + t6);
            float h1 = h0 - t0 + t7;
            float h2 = h1 - t1 + t8;
            float h3 = h2 - t2 + t9;
            float w0 = __builtin_amdgcn_exp2f(h0 * K);
            float w1 = __builtin_amdgcn_exp2f(h1 * K);
            float w2 = __builtin_amdgcn_exp2f(h2 * K);
            float w3 = __builtin_amdgcn_exp2f(h3 * K);
            float a0 = xs[svb + ox];
            float a1 = xs[svb + ox + 1];
            float a2 = xs[svb + ox + 2];
            float a3 = xs[svb + ox + 3];
            ws0 += w0; vs0 = fmaf(w0, a0, vs0);
            ws1 += w1; vs1 = fmaf(w1, a1, vs1);
            ws2 += w2; vs2 = fmaf(w2, a2, vs2);
            ws3 += w3; vs3 = fmaf(w3, a3, vs3);
            // next A (ds writes) is fenced from this Bv's reads by the bar
            // after A; this C's vs reads are fenced from next Bv's writes by
            // that same bar. 2 barriers/offset.
        }
#pragma unroll
        for (int k = 0; k < 6; ++k) ra[k] += XSTR;
        svb += XSTR;
    }

    float4 o;
    o.x = fminf(fmaxf(vs0 * __builtin_amdgcn_rcpf(ws0), 0.f), 1.f);
    o.y = fminf(fmaxf(vs1 * __builtin_amdgcn_rcpf(ws1), 0.f), 1.f);
    o.z = fminf(fmaxf(vs2 * __builtin_amdgcn_rcpf(ws2), 0.f), 1.f);
    o.w = fminf(fmaxf(vs3 * __builtin_amdgcn_rcpf(ws3), 0.f), 1.f);
    *reinterpret_cast<float4*>(
        &out[((size_t)blockIdx.z * H + (gy0 + py)) * W + (gx0 + c4)]) = o;
}

extern "C" void kernel_launch(void* const* d_in, const int* in_sizes, int n_in,
                              void* d_out, int out_size, void* d_ws, size_t ws_size,
                              hipStream_t stream) {
    const float* x = (const float*)d_in[0];
    float* out = (float*)d_out;
    const int H = 1024, W = 1024;
    const int B = in_sizes[0] / (H * W);
    dim3 grid(W / TS, H / TS, B);
    nlm_kernel<<<grid, dim3(256), 0, stream>>>(x, out, H, W);
}

// Round 3
// 1625.903 us; speedup vs baseline: 6.5912x; 6.5912x over previous
//
#include <hip/hip_runtime.h>
#include <cstddef>

// NLM: h=7/255, template 7x7 (TH=3), search 21x21 (SH=10), reflect padding.
// Tile 32x32/block, 256 threads. Per offset:
//   A : d = (u - shifted)^2 into ds; 6 elems/thread as 3 adjacent pairs,
//       u preloaded in regs (offset-invariant), named-scalar addresses.
//   Bv: vertical 7-sums, register sliding; threads 0..151 (38 cols x 4 row
//       groups), 8 output rows each: 14 reads -> 8 writes.
//   C : horizontal 7-sum sliding + exp2 weight + accumulate; 1 row x 4 cols
//       per thread.
// NOTE R2 post-mortem: full ox-unroll + launch_bounds(256,6) caused scratch
// demotion (35 GB/dispatch HBM). This version: named scalars only, ox loop
// NOT unrolled, no occupancy request.

constexpr int TS    = 32;
constexpr int XSTR  = 61;       // odd stride -> benign <=2-way bank aliasing
constexpr int XROWS = 59;       // image rows gy0-13 .. gy0+45
constexpr int XSZ   = XROWS * XSTR;            // 3599
constexpr int DSTR  = 41;
constexpr int DS_SZ = 37 * DSTR + 40;          // 38 rows used, 40 cols stored
constexpr int VSTR  = 39;
constexpr int VS_SZ = 31 * VSTR + 38;          // 32 rows x 38 cols

__device__ __forceinline__ int refl(int i, int n) {
    i = (i < 0) ? -i : i;
    return (i >= n) ? (2 * n - 2 - i) : i;
}

__global__ __launch_bounds__(256)
void nlm_kernel(const float* __restrict__ img_all, float* __restrict__ out,
                int H, int W) {
    __shared__ float xs[XSZ];
    __shared__ float ds[DS_SZ];
    __shared__ float vsh[VS_SZ];

    const int tid = threadIdx.x;
    const int gx0 = blockIdx.x * TS;
    const int gy0 = blockIdx.y * TS;
    const float* img = img_all + (size_t)blockIdx.z * H * W;

    // ---- load xs (clip to [0,1], reflect indexing), all rows valid ----
    for (int e = tid; e < XSZ; e += 256) {
        int i = e / XSTR, j = e - i * XSTR;
        int jj = (j > 57) ? 57 : j;   // cols 58..60 are stride pad only
        int gy = refl(gy0 - 13 + i, H);
        int gx = refl(gx0 - 13 + jj, W);
        float v = img[(size_t)gy * W + gx];
        xs[e] = fminf(fmaxf(v, 0.0f), 1.0f);
    }
    __syncthreads();

    // ---- stage-A constants: 38 rows x 20 pairs = 760 pairs over 768 slots;
    // last 8 threads duplicate pair 759 (same value, benign LDS write).
    // d element (arow, acol) <-> image (gy0+arow-3, gx0+acol-3); box-filter
    // reflect folded via refl() into xs coords.
    int ra0, ra1, ra2, ra3, ra4, ra5;   // xs read base (at oy=0: dy=-10,dx=-10)
    int wa0, wa1, wa2;                  // ds write base (pair-adjacent)
    float uv0, uv1, uv2, uv3, uv4, uv5;
    {
        int p0 = tid, p1 = tid + 256, p2 = (tid + 512 > 759) ? 759 : tid + 512;
        int r0_ = p0 / 20, c0_ = (p0 - r0_ * 20) * 2;
        int r1_ = p1 / 20, c1_ = (p1 - r1_ * 20) * 2;
        int r2_ = p2 / 20, c2_ = (p2 - r2_ * 20) * 2;
        int my0 = refl(gy0 + r0_ - 3, H) - gy0 + 13;
        int my1 = refl(gy0 + r1_ - 3, H) - gy0 + 13;
        int my2 = refl(gy0 + r2_ - 3, H) - gy0 + 13;
        int mxa = refl(gx0 + c0_ - 3, W) - gx0 + 13;
        int mxb = refl(gx0 + c0_ - 2, W) - gx0 + 13;
        int mxc = refl(gx0 + c1_ - 3, W) - gx0 + 13;
        int mxd = refl(gx0 + c1_ - 2, W) - gx0 + 13;
        int mxe = refl(gx0 + c2_ - 3, W) - gx0 + 13;
        int mxf = refl(gx0 + c2_ - 2, W) - gx0 + 13;
        uv0 = xs[my0 * XSTR + mxa];  ra0 = (my0 - 10) * XSTR + (mxa - 10);
        uv1 = xs[my0 * XSTR + mxb];  ra1 = (my0 - 10) * XSTR + (mxb - 10);
        uv2 = xs[my1 * XSTR + mxc];  ra2 = (my1 - 10) * XSTR + (mxc - 10);
        uv3 = xs[my1 * XSTR + mxd];  ra3 = (my1 - 10) * XSTR + (mxd - 10);
        uv4 = xs[my2 * XSTR + mxe];  ra4 = (my2 - 10) * XSTR + (mxe - 10);
        uv5 = xs[my2 * XSTR + mxf];  ra5 = (my2 - 10) * XSTR + (mxf - 10);
        wa0 = r0_ * DSTR + c0_;
        wa1 = r1_ * DSTR + c1_;
        wa2 = r2_ * DSTR + c2_;
    }

    // ---- stage-Bv constants: threads 0..151 = 38 cols x 4 row-groups ----
    const bool bv_act = (tid < 152);
    int rb, wb;
    {
        int t  = bv_act ? tid : 0;
        int g  = t / 38;
        int cc = t - g * 38;
        rb = (g * 8) * DSTR + cc;
        wb = (g * 8) * VSTR + cc;
    }

    // ---- stage-C constants ----
    const int py = tid >> 3;
    const int c4 = (tid & 7) * 4;
    const int vb = py * VSTR + c4;
    int svb = (py + 3) * XSTR + (c4 + 3);   // shifted value base at dy=dx=-10

    float ws0 = 0.f, ws1 = 0.f, ws2 = 0.f, ws3 = 0.f;
    float ac0 = 0.f, ac1 = 0.f, ac2 = 0.f, ac3 = 0.f;
    // w = exp(-mean49(d)/H2) = exp2(K * sum49(d))
    const float K = -(65025.0f / 2401.0f) * 1.4426950408889634f;

    for (int oy = 0; oy < 21; ++oy) {
#pragma unroll 1
        for (int ox = 0; ox < 21; ++ox) {
            // ---- A ----
            {
                float d0 = uv0 - xs[ra0 + ox];
                float d1 = uv1 - xs[ra1 + ox];
                float d2 = uv2 - xs[ra2 + ox];
                float d3 = uv3 - xs[ra3 + ox];
                float d4 = uv4 - xs[ra4 + ox];
                float d5 = uv5 - xs[ra5 + ox];
                ds[wa0]     = d0 * d0;
                ds[wa0 + 1] = d1 * d1;
                ds[wa1]     = d2 * d2;
                ds[wa1 + 1] = d3 * d3;
                ds[wa2]     = d4 * d4;
                ds[wa2 + 1] = d5 * d5;
            }
            __syncthreads();

            // ---- Bv ----
            if (bv_act) {
                float r0  = ds[rb];
                float r1  = ds[rb + 1 * DSTR];
                float r2  = ds[rb + 2 * DSTR];
                float r3  = ds[rb + 3 * DSTR];
                float r4  = ds[rb + 4 * DSTR];
                float r5  = ds[rb + 5 * DSTR];
                float r6  = ds[rb + 6 * DSTR];
                float r7  = ds[rb + 7 * DSTR];
                float r8  = ds[rb + 8 * DSTR];
                float r9  = ds[rb + 9 * DSTR];
                float r10 = ds[rb + 10 * DSTR];
                float r11 = ds[rb + 11 * DSTR];
                float r12 = ds[rb + 12 * DSTR];
                float r13 = ds[rb + 13 * DSTR];
                float s = ((r0 + r1) + (r2 + r3)) + ((r4 + r5) + r6);
                vsh[wb]            = s;
                s += r7  - r0;  vsh[wb + 1 * VSTR] = s;
                s += r8  - r1;  vsh[wb + 2 * VSTR] = s;
                s += r9  - r2;  vsh[wb + 3 * VSTR] = s;
                s += r10 - r3;  vsh[wb + 4 * VSTR] = s;
                s += r11 - r4;  vsh[wb + 5 * VSTR] = s;
                s += r12 - r5;  vsh[wb + 6 * VSTR] = s;
                s += r13 - r6;  vsh[wb + 7 * VSTR] = s;
            }
            __syncthreads();

            // ---- C ----
            float t0 = vsh[vb];
            float t1 = vsh[vb + 1];
            float t2 = vsh[vb + 2];
            float t3 = vsh[vb + 3];
            float t4 = vsh[vb + 4];
            float t5 = vsh[vb + 5];
            float t6 = vsh[vb + 6];
            float t7 = vsh[vb + 7];
            float t8 = vsh[vb + 8];
            float t9 = vsh[vb + 9];
            float h0 = ((t0 + t1) + (t2 + t3)) + ((t4 + t5) + t6);
            float h1 = h0 - t0 + t7;
            float h2 = h1 - t1 + t8;
            float h3 = h2 - t2 + t9;
            float w0 = __builtin_amdgcn_exp2f(h0 * K);
            float w1 = __builtin_amdgcn_exp2f(h1 * K);
            float w2 = __builtin_amdgcn_exp2f(h2 * K);
            float w3 = __builtin_amdgcn_exp2f(h3 * K);
            float a0 = xs[svb + ox];
            float a1 = xs[svb + ox + 1];
            float a2 = xs[svb + ox + 2];
            float a3 = xs[svb + ox + 3];
            ws0 += w0; ac0 = fmaf(w0, a0, ac0);
            ws1 += w1; ac1 = fmaf(w1, a1, ac1);
            ws2 += w2; ac2 = fmaf(w2, a2, ac2);
            ws3 += w3; ac3 = fmaf(w3, a3, ac3);
            // next A's ds writes are fenced from this Bv's reads by the
            // post-A barrier; this C's vsh reads are fenced from next Bv's
            // writes by the same barrier. 2 barriers/offset.
        }
        ra0 += XSTR; ra1 += XSTR; ra2 += XSTR;
        ra3 += XSTR; ra4 += XSTR; ra5 += XSTR;
        svb += XSTR;
    }

    float4 o;
    o.x = fminf(fmaxf(ac0 * __builtin_amdgcn_rcpf(ws0), 0.f), 1.f);
    o.y = fminf(fmaxf(ac1 * __builtin_amdgcn_rcpf(ws1), 0.f), 1.f);
    o.z = fminf(fmaxf(ac2 * __builtin_amdgcn_rcpf(ws2), 0.f), 1.f);
    o.w = fminf(fmaxf(ac3 * __builtin_amdgcn_rcpf(ws3), 0.f), 1.f);
    *reinterpret_cast<float4*>(
        &out[((size_t)blockIdx.z * H + (gy0 + py)) * W + (gx0 + c4)]) = o;
}

extern "C" void kernel_launch(void* const* d_in, const int* in_sizes, int n_in,
                              void* d_out, int out_size, void* d_ws, size_t ws_size,
                              hipStream_t stream) {
    const float* x = (const float*)d_in[0];
    float* out = (float*)d_out;
    const int H = 1024, W = 1024;
    const int B = in_sizes[0] / (H * W);
    dim3 grid(W / TS, H / TS, B);
    nlm_kernel<<<grid, dim3(256), 0, stream>>>(x, out, H, W);
}

// Round 4
// 1131.124 us; speedup vs baseline: 9.4744x; 1.4374x over previous
//
#include <hip/hip_runtime.h>
#include <cstddef>

// NLM: h=7/255, template 7x7 (TH=3), search 21x21 (SH=10), reflect padding.
// Tile 32x32/block, 256 threads. Per offset (fused two-stage):
//   Bv (tid 0..151 = 38 cols x 4 groups of 8 rows): d computed on the fly
//       (u in regs, offset-invariant; shifted value = 1 ds_read each of 14
//       rows via per-lane incremental addresses -> edge reflection exact),
//       vertical 7-sum register sliding -> 8 vsh writes.
//   C  (tid 128..255 = 32 rows x 4 groups of 8 cols): 7x float2 vsh reads,
//       horizontal 7-sum sliding, 8x exp2 weights, shifted center values via
//       1-read/ox sliding register window, accumulate; 2x float4 store.
// R2 lesson: named scalars only, no unrolling of offset loops.

constexpr int TS    = 32;
constexpr int XSTR  = 61;            // odd -> benign bank aliasing
constexpr int XROWS = 59;            // image rows gy0-13 .. gy0+45
constexpr int XSZ   = XROWS * XSTR;  // 3599
constexpr int VSTR  = 42;            // even (float2-aligned), 42%8!=0 (banks ok)
constexpr int VS_SZ = 32 * VSTR;     // 1344

__device__ __forceinline__ int refl(int i, int n) {
    i = (i < 0) ? -i : i;
    return (i >= n) ? (2 * n - 2 - i) : i;
}

__global__ __launch_bounds__(256)
void nlm_kernel(const float* __restrict__ img_all, float* __restrict__ out,
                int H, int W) {
    __shared__ float xs[XSZ];
    __shared__ float vsh[VS_SZ];

    const int tid = threadIdx.x;
    const int gx0 = blockIdx.x * TS;
    const int gy0 = blockIdx.y * TS;
    const float* img = img_all + (size_t)blockIdx.z * H * W;

    // ---- load xs (clip to [0,1], reflect indexing) ----
    for (int e = tid; e < XSZ; e += 256) {
        int i = e / XSTR, j = e - i * XSTR;
        int jj = (j > 57) ? 57 : j;  // cols 58..60: stride pad (never read)
        int gy = refl(gy0 - 13 + i, H);
        int gx = refl(gx0 - 13 + jj, W);
        float v = img[(size_t)gy * W + gx];
        xs[e] = fminf(fmaxf(v, 0.0f), 1.0f);
    }
    __syncthreads();

    // ---- Bv setup: u values + read addresses for 14 rows of one d-column.
    // d element (arow=g*8+i, acol=cc) <-> image (gy0+arow-3, gx0+cc-3),
    // reflect-mapped to (my, mx) in xs space. Shifted read = xs[(my+dy)*XSTR
    // + (mx+dx)], maintained incrementally (a_i += 1 per ox, += XSTR-21/oy).
    const bool bv = (tid < 152);
    float u0,u1,u2,u3,u4,u5,u6,u7,u8,u9,u10,u11,u12,u13;
    int   a0,a1,a2,a3,a4,a5,a6,a7,a8,a9,a10,a11,a12,a13;
    int   wb;
    {
        int t  = bv ? tid : 0;
        int g  = t / 38;
        int cc = t - g * 38;
        int mx = refl(gx0 + cc - 3, W) - gx0 + 13;
        int r  = g * 8;
#define BV_INIT(i) { int my = refl(gy0 + r + i - 3, H) - gy0 + 13; \
                     u##i = xs[my * XSTR + mx]; \
                     a##i = (my - 10) * XSTR + (mx - 10); }
        BV_INIT(0)  BV_INIT(1)  BV_INIT(2)  BV_INIT(3)
        BV_INIT(4)  BV_INIT(5)  BV_INIT(6)  BV_INIT(7)
        BV_INIT(8)  BV_INIT(9)  BV_INIT(10) BV_INIT(11)
        BV_INIT(12) BV_INIT(13)
#undef BV_INIT
        wb = r * VSTR + cc;
    }

    // ---- C setup ----
    const bool cact = (tid >= 128);
    const int ct = cact ? (tid - 128) : 0;
    const int py = ct >> 2;
    const int c8 = (ct & 3) * 8;
    const int vb = py * VSTR + c8;              // float2-aligned (even)
    int sv = (py + 3) * XSTR + (c8 + 3);        // window base at oy=0

    float ws0=0.f,ws1=0.f,ws2=0.f,ws3=0.f,ws4=0.f,ws5=0.f,ws6=0.f,ws7=0.f;
    float ac0=0.f,ac1=0.f,ac2=0.f,ac3=0.f,ac4=0.f,ac5=0.f,ac6=0.f,ac7=0.f;
    // w = exp(-mean49(d)/H2) = exp2(K * sum49(d))
    const float K = -(65025.0f / 2401.0f) * 1.4426950408889634f;

#pragma unroll 1
    for (int oy = 0; oy < 21; ++oy) {
        float p0,p1,p2,p3,p4,p5,p6;
        if (cact) {
            p0 = xs[sv];     p1 = xs[sv + 1]; p2 = xs[sv + 2];
            p3 = xs[sv + 3]; p4 = xs[sv + 4]; p5 = xs[sv + 5];
            p6 = xs[sv + 6];
        }
        const int svo = sv + 7;
#pragma unroll 1
        for (int ox = 0; ox < 21; ++ox) {
            // ---- Bv: fused d + vertical 7-sum sliding ----
            if (bv) {
                float d, s;
                float q0,q1,q2,q3,q4,q5,q6,q7,q8,q9,q10,q11,q12,q13;
                d = u0  - xs[a0];  q0  = d * d;
                d = u1  - xs[a1];  q1  = d * d;
                d = u2  - xs[a2];  q2  = d * d;
                d = u3  - xs[a3];  q3  = d * d;
                d = u4  - xs[a4];  q4  = d * d;
                d = u5  - xs[a5];  q5  = d * d;
                d = u6  - xs[a6];  q6  = d * d;
                d = u7  - xs[a7];  q7  = d * d;
                d = u8  - xs[a8];  q8  = d * d;
                d = u9  - xs[a9];  q9  = d * d;
                d = u10 - xs[a10]; q10 = d * d;
                d = u11 - xs[a11]; q11 = d * d;
                d = u12 - xs[a12]; q12 = d * d;
                d = u13 - xs[a13]; q13 = d * d;
                s = ((q0 + q1) + (q2 + q3)) + ((q4 + q5) + q6);
                vsh[wb]            = s;
                s += q7  - q0;  vsh[wb + 1 * VSTR] = s;
                s += q8  - q1;  vsh[wb + 2 * VSTR] = s;
                s += q9  - q2;  vsh[wb + 3 * VSTR] = s;
                s += q10 - q3;  vsh[wb + 4 * VSTR] = s;
                s += q11 - q4;  vsh[wb + 5 * VSTR] = s;
                s += q12 - q5;  vsh[wb + 6 * VSTR] = s;
                s += q13 - q6;  vsh[wb + 7 * VSTR] = s;
                a0 += 1;  a1 += 1;  a2 += 1;  a3 += 1;  a4 += 1;
                a5 += 1;  a6 += 1;  a7 += 1;  a8 += 1;  a9 += 1;
                a10 += 1; a11 += 1; a12 += 1; a13 += 1;
            }
            __syncthreads();

            // ---- C: horizontal 7-sum sliding + weights + accumulate ----
            if (cact) {
                const float2* vp = reinterpret_cast<const float2*>(&vsh[vb]);
                float2 tA = vp[0], tB = vp[1], tC = vp[2], tD = vp[3];
                float2 tE = vp[4], tF = vp[5], tG = vp[6];
                float p7 = xs[svo + ox];
                float h0 = ((tA.x + tA.y) + (tB.x + tB.y)) + ((tC.x + tC.y) + tD.x);
                float h1 = h0 - tA.x + tD.y;
                float h2 = h1 - tA.y + tE.x;
                float h3 = h2 - tB.x + tE.y;
                float h4 = h3 - tB.y + tF.x;
                float h5 = h4 - tC.x + tF.y;
                float h6 = h5 - tC.y + tG.x;
                float h7 = h6 - tD.x + tG.y;
                float w;
                w = __builtin_amdgcn_exp2f(h0 * K); ws0 += w; ac0 = fmaf(w, p0, ac0);
                w = __builtin_amdgcn_exp2f(h1 * K); ws1 += w; ac1 = fmaf(w, p1, ac1);
                w = __builtin_amdgcn_exp2f(h2 * K); ws2 += w; ac2 = fmaf(w, p2, ac2);
                w = __builtin_amdgcn_exp2f(h3 * K); ws3 += w; ac3 = fmaf(w, p3, ac3);
                w = __builtin_amdgcn_exp2f(h4 * K); ws4 += w; ac4 = fmaf(w, p4, ac4);
                w = __builtin_amdgcn_exp2f(h5 * K); ws5 += w; ac5 = fmaf(w, p5, ac5);
                w = __builtin_amdgcn_exp2f(h6 * K); ws6 += w; ac6 = fmaf(w, p6, ac6);
                w = __builtin_amdgcn_exp2f(h7 * K); ws7 += w; ac7 = fmaf(w, p7, ac7);
                p0 = p1; p1 = p2; p2 = p3; p3 = p4; p4 = p5; p5 = p6; p6 = p7;
            }
            __syncthreads();
            // C's vsh reads are fenced from next Bv's writes by the 2nd bar;
            // Bv's writes are fenced from C's reads by the 1st. 2 bars/offset.
        }
        if (bv) {
            a0 += XSTR - 21;  a1 += XSTR - 21;  a2 += XSTR - 21;
            a3 += XSTR - 21;  a4 += XSTR - 21;  a5 += XSTR - 21;
            a6 += XSTR - 21;  a7 += XSTR - 21;  a8 += XSTR - 21;
            a9 += XSTR - 21;  a10 += XSTR - 21; a11 += XSTR - 21;
            a12 += XSTR - 21; a13 += XSTR - 21;
        }
        sv += XSTR;
    }

    if (cact) {
        float4 oA, oB;
        oA.x = fminf(fmaxf(ac0 * __builtin_amdgcn_rcpf(ws0), 0.f), 1.f);
        oA.y = fminf(fmaxf(ac1 * __builtin_amdgcn_rcpf(ws1), 0.f), 1.f);
        oA.z = fminf(fmaxf(ac2 * __builtin_amdgcn_rcpf(ws2), 0.f), 1.f);
        oA.w = fminf(fmaxf(ac3 * __builtin_amdgcn_rcpf(ws3), 0.f), 1.f);
        oB.x = fminf(fmaxf(ac4 * __builtin_amdgcn_rcpf(ws4), 0.f), 1.f);
        oB.y = fminf(fmaxf(ac5 * __builtin_amdgcn_rcpf(ws5), 0.f), 1.f);
        oB.z = fminf(fmaxf(ac6 * __builtin_amdgcn_rcpf(ws6), 0.f), 1.f);
        oB.w = fminf(fmaxf(ac7 * __builtin_amdgcn_rcpf(ws7), 0.f), 1.f);
        float* op = &out[((size_t)blockIdx.z * H + (gy0 + py)) * W + (gx0 + c8)];
        *reinterpret_cast<float4*>(op)     = oA;
        *reinterpret_cast<float4*>(op + 4) = oB;
    }
}

extern "C" void kernel_launch(void* const* d_in, const int* in_sizes, int n_in,
                              void* d_out, int out_size, void* d_ws, size_t ws_size,
                              hipStream_t stream) {
    const float* x = (const float*)d_in[0];
    float* out = (float*)d_out;
    const int H = 1024, W = 1024;
    const int B = in_sizes[0] / (H * W);
    dim3 grid(W / TS, H / TS, B);
    nlm_kernel<<<grid, dim3(256), 0, stream>>>(x, out, H, W);
}